// Round 2
// baseline (813.066 us; speedup 1.0000x reference)
//
#include <hip/hip_runtime.h>
#include <math.h>

#define NT 256
#define BM 32
#define M_TOTAL 16384
#define K_DIM 2048
#define E_DIM 64

__global__ __launch_bounds__(NT, 2) void router_topk_kernel(
    const float* __restrict__ x,
    const float* __restrict__ router_w,
    const float* __restrict__ noise_w,
    const float* __restrict__ router_b,
    const float* __restrict__ noise_b,
    const float* __restrict__ noise_u,
    float* __restrict__ out)
{
    __shared__ struct {
        float Cs[BM][132];
        float p1v[BM]; float p2v[BM];
        int   i1v[BM]; int   i2v[BM];
    } sm;

    const int t = threadIdx.x;
    const int rowBase = blockIdx.x * BM;
    const int cg = t & 31;   // column group: 4 cols each, 0..31 -> 128 cols
    const int rg = t >> 5;   // row group: 4 rows each, 0..7 -> 32 rows

    // A: this thread's 4 rows (within a wave only 2 distinct rg -> broadcast loads)
    const float* xrow = x + (size_t)(rowBase + rg * 4) * K_DIM;
    // B: this thread's 4 columns. cols 0..63 = router_w, 64..127 = noise_w
    const float* wbase = (cg < 16)
        ? (router_w + (size_t)(cg * 4) * K_DIM)
        : (noise_w + (size_t)((cg - 16) * 4) * K_DIM);

    float acc[4][4];
    #pragma unroll
    for (int i = 0; i < 4; ++i)
        #pragma unroll
        for (int j = 0; j < 4; ++j) acc[i][j] = 0.0f;

    float4 acur[4], bcur[4], anxt[4], bnxt[4];

    #pragma unroll
    for (int i = 0; i < 4; ++i) acur[i] = *(const float4*)(xrow + (size_t)i * K_DIM);
    #pragma unroll
    for (int j = 0; j < 4; ++j) bcur[j] = *(const float4*)(wbase + (size_t)j * K_DIM);

    const int NGROUP = K_DIM / 4;  // 512
    for (int kg = 0; kg < NGROUP - 1; ++kg) {
        const int off = (kg + 1) * 4;
        #pragma unroll
        for (int i = 0; i < 4; ++i) anxt[i] = *(const float4*)(xrow + (size_t)i * K_DIM + off);
        #pragma unroll
        for (int j = 0; j < 4; ++j) bnxt[j] = *(const float4*)(wbase + (size_t)j * K_DIM + off);

        #pragma unroll
        for (int kk = 0; kk < 4; ++kk) {
            #pragma unroll
            for (int i = 0; i < 4; ++i) {
                const float a = ((const float*)&acur[i])[kk];
                #pragma unroll
                for (int j = 0; j < 4; ++j)
                    acc[i][j] = fmaf(a, ((const float*)&bcur[j])[kk], acc[i][j]);
            }
        }
        #pragma unroll
        for (int i = 0; i < 4; ++i) acur[i] = anxt[i];
        #pragma unroll
        for (int j = 0; j < 4; ++j) bcur[j] = bnxt[j];
    }
    // last group
    #pragma unroll
    for (int kk = 0; kk < 4; ++kk) {
        #pragma unroll
        for (int i = 0; i < 4; ++i) {
            const float a = ((const float*)&acur[i])[kk];
            #pragma unroll
            for (int j = 0; j < 4; ++j)
                acc[i][j] = fmaf(a, ((const float*)&bcur[j])[kk], acc[i][j]);
        }
    }

    // ---- epilogue ----
    #pragma unroll
    for (int i = 0; i < 4; ++i) {
        float4 v;
        v.x = acc[i][0]; v.y = acc[i][1]; v.z = acc[i][2]; v.w = acc[i][3];
        *(float4*)&sm.Cs[rg * 4 + i][cg * 4] = v;
    }
    __syncthreads();

    if (t < BM) {
        const int r = t;
        const int grow = rowBase + r;
        const float* urow = noise_u + (size_t)grow * E_DIM;
        float v1 = -3.0e38f, v2 = -3.0e38f;
        int i1 = 0, i2 = 0;
        for (int e = 0; e < E_DIM; ++e) {
            const float lg = sm.Cs[r][e] + router_b[e];
            const float nz = sm.Cs[r][64 + e] + noise_b[e];
            const float sp = fmaxf(nz, 0.0f) + log1pf(expf(-fabsf(nz)));
            const float nv = lg + sp * urow[e];
            if (nv > v1) { v2 = v1; i2 = i1; v1 = nv; i1 = e; }
            else if (nv > v2) { v2 = nv; i2 = e; }
        }
        const float e2 = expf(v2 - v1);
        const float denom = 1.0f + e2;   // other 62 slots contribute exp(-1e30 - m) == 0
        sm.p1v[r] = 1.0f / denom;
        sm.p2v[r] = e2 / denom;
        sm.i1v[r] = i1;
        sm.i2v[r] = i2;
        float2 idx2;
        idx2.x = (float)i1;
        idx2.y = (float)i2;
        *(float2*)&out[(size_t)M_TOTAL * E_DIM + (size_t)grow * 2] = idx2;
    }
    __syncthreads();

    // cooperative sparse-softmax write: 32 rows x 64 experts = 2048 floats, 8/thread
    {
        const int r  = t >> 3;
        const int eb = (t & 7) * 8;
        const int grow = rowBase + r;
        const int i1 = sm.i1v[r];
        const int i2 = sm.i2v[r];
        const float p1 = sm.p1v[r];
        const float p2 = sm.p2v[r];
        float* orow = out + (size_t)grow * E_DIM;
        #pragma unroll
        for (int g = 0; g < 2; ++g) {
            const int e0 = eb + g * 4;
            float4 v;
            v.x = (e0 + 0 == i1) ? p1 : (e0 + 0 == i2) ? p2 : 0.0f;
            v.y = (e0 + 1 == i1) ? p1 : (e0 + 1 == i2) ? p2 : 0.0f;
            v.z = (e0 + 2 == i1) ? p1 : (e0 + 2 == i2) ? p2 : 0.0f;
            v.w = (e0 + 3 == i1) ? p1 : (e0 + 3 == i2) ? p2 : 0.0f;
            *(float4*)&orow[e0] = v;
        }
    }
}

extern "C" void kernel_launch(void* const* d_in, const int* in_sizes, int n_in,
                              void* d_out, int out_size, void* d_ws, size_t ws_size,
                              hipStream_t stream) {
    const float* x  = (const float*)d_in[0];
    const float* rw = (const float*)d_in[1];
    const float* rb = (const float*)d_in[2];
    const float* nw = (const float*)d_in[3];
    const float* nb = (const float*)d_in[4];
    const float* nu = (const float*)d_in[5];
    float* out = (float*)d_out;
    (void)in_sizes; (void)n_in; (void)out_size; (void)d_ws; (void)ws_size;

    hipLaunchKernelGGL(router_topk_kernel, dim3(M_TOTAL / BM), dim3(NT), 0, stream,
                       x, rw, nw, rb, nb, nu, out);
}

// Round 4
// 244.004 us; speedup vs baseline: 3.3322x; 3.3322x over previous
//
#include <hip/hip_runtime.h>
#include <math.h>

typedef __fp16   fp16x2  __attribute__((ext_vector_type(2)));
typedef _Float16 half8   __attribute__((ext_vector_type(8)));
typedef float    floatx4 __attribute__((ext_vector_type(4)));

#define M_TOTAL 16384
#define K_DIM   2048
#define E_DIM   64
#define NCOL    128      // 64 router + 64 noise
#define BMg     64
#define BKg     32
#define NT      256
#define KSLICE  2
#define KPER    (K_DIM / KSLICE)   // 1024
#define NCHUNK  (KPER / BKg)       // 32
#define LDA     40                  // f16 row stride (32 data + 8 pad, 80 B: 16B-aligned rows)

// per-buffer f16 offsets
#define OFF_AHI 0
#define OFF_ALO (BMg * LDA)              // 2560
#define OFF_BHI (2 * BMg * LDA)          // 5120
#define OFF_BLO (2 * BMg * LDA + NCOL * LDA)  // 10240
#define BUFSZ   (2 * BMg * LDA + 2 * NCOL * LDA)  // 15360

__device__ __forceinline__ void cvt_store(const float4 v, _Float16* hiP, _Float16* loP) {
    fp16x2 h01 = __builtin_amdgcn_cvt_pkrtz(v.x, v.y);
    fp16x2 h23 = __builtin_amdgcn_cvt_pkrtz(v.z, v.w);
    float r0 = (v.x - (float)h01.x) * 2048.0f;
    float r1 = (v.y - (float)h01.y) * 2048.0f;
    float r2 = (v.z - (float)h23.x) * 2048.0f;
    float r3 = (v.w - (float)h23.y) * 2048.0f;
    fp16x2 l01 = __builtin_amdgcn_cvt_pkrtz(r0, r1);
    fp16x2 l23 = __builtin_amdgcn_cvt_pkrtz(r2, r3);
    union { fp16x2 h[2]; uint2 u; } ph, pl;
    ph.h[0] = h01; ph.h[1] = h23;
    pl.h[0] = l01; pl.h[1] = l23;
    *(uint2*)hiP = ph.u;
    *(uint2*)loP = pl.u;
}

__global__ __launch_bounds__(NT, 2) void gemm_split_kernel(
    const float* __restrict__ x,
    const float* __restrict__ router_w,
    const float* __restrict__ noise_w,
    float* __restrict__ ws)
{
    __shared__ __align__(16) _Float16 S[2 * BUFSZ];

    const int t = threadIdx.x;
    const int mblk  = blockIdx.x >> 1;
    const int slice = blockIdx.x & 1;
    const int rowBase = mblk * BMg;
    const int kBase   = slice * KPER;

    // staging map: r = row/col index 0..31, q = float4 index within 32-k chunk
    const int r = t >> 3;
    const int q = t & 7;

    const float* pa0 = x + (size_t)(rowBase + r) * K_DIM + kBase + q * 4;
    const float* pa1 = pa0 + (size_t)32 * K_DIM;
    const float* pb0 = router_w + (size_t)r * K_DIM + kBase + q * 4;        // col r
    const float* pb1 = pb0 + (size_t)32 * K_DIM;                            // col r+32
    const float* pb2 = noise_w + (size_t)r * K_DIM + kBase + q * 4;         // col r+64
    const float* pb3 = pb2 + (size_t)32 * K_DIM;                            // col r+96

    const int wa0 = r * LDA + q * 4;
    const int wa1 = (r + 32) * LDA + q * 4;
    const int wb0 = r * LDA + q * 4;
    const int wb1 = (r + 32) * LDA + q * 4;
    const int wb2 = (r + 64) * LDA + q * 4;
    const int wb3 = (r + 96) * LDA + q * 4;

    // fragment map
    const int lane = t & 63;
    const int w    = t >> 6;
    const int mt0  = (w & 1) * 32;
    const int nt0  = (w >> 1) * 64;
    const int lr   = lane & 15;
    const int lk   = (lane >> 4) * 8;
    const int aOff = (mt0 + lr) * LDA + lk;
    const int bOff = (nt0 + lr) * LDA + lk;

    floatx4 acch[2][4], accx[2][4];
    #pragma unroll
    for (int mi = 0; mi < 2; ++mi)
        #pragma unroll
        for (int ni = 0; ni < 4; ++ni) {
            acch[mi][ni] = (floatx4)0.0f;
            accx[mi][ni] = (floatx4)0.0f;
        }

    // prefetch chunk 0
    float4 a0v = *(const float4*)pa0;
    float4 a1v = *(const float4*)pa1;
    float4 b0v = *(const float4*)pb0;
    float4 b1v = *(const float4*)pb1;
    float4 b2v = *(const float4*)pb2;
    float4 b3v = *(const float4*)pb3;

    for (int c = 0; c < NCHUNK; ++c) {
        _Float16* buf = S + (c & 1) * BUFSZ;

        // (D) convert + write chunk c into buf[c&1]
        cvt_store(a0v, &buf[OFF_AHI + wa0], &buf[OFF_ALO + wa0]);
        cvt_store(a1v, &buf[OFF_AHI + wa1], &buf[OFF_ALO + wa1]);
        cvt_store(b0v, &buf[OFF_BHI + wb0], &buf[OFF_BLO + wb0]);
        cvt_store(b1v, &buf[OFF_BHI + wb1], &buf[OFF_BLO + wb1]);
        cvt_store(b2v, &buf[OFF_BHI + wb2], &buf[OFF_BLO + wb2]);
        cvt_store(b3v, &buf[OFF_BHI + wb3], &buf[OFF_BLO + wb3]);

        // (B) issue prefetch for chunk c+1
        if (c + 1 < NCHUNK) {
            const int off = (c + 1) * BKg;
            a0v = *(const float4*)(pa0 + off);
            a1v = *(const float4*)(pa1 + off);
            b0v = *(const float4*)(pb0 + off);
            b1v = *(const float4*)(pb1 + off);
            b2v = *(const float4*)(pb2 + off);
            b3v = *(const float4*)(pb3 + off);
        }

        // (C) one barrier per chunk
        __syncthreads();

        // (A) fragment reads
        half8 ah[2], al[2], bh[4], bl[4];
        #pragma unroll
        for (int mi = 0; mi < 2; ++mi) {
            ah[mi] = *(const half8*)&buf[OFF_AHI + aOff + mi * 16 * LDA];
            al[mi] = *(const half8*)&buf[OFF_ALO + aOff + mi * 16 * LDA];
        }
        #pragma unroll
        for (int ni = 0; ni < 4; ++ni) {
            bh[ni] = *(const half8*)&buf[OFF_BHI + bOff + ni * 16 * LDA];
            bl[ni] = *(const half8*)&buf[OFF_BLO + bOff + ni * 16 * LDA];
        }

        // (E) MFMA: C = hi*hi + (hi*lo' + lo'*hi) * 2^-11
        #pragma unroll
        for (int mi = 0; mi < 2; ++mi)
            #pragma unroll
            for (int ni = 0; ni < 4; ++ni) {
                acch[mi][ni] = __builtin_amdgcn_mfma_f32_16x16x32_f16(ah[mi], bh[ni], acch[mi][ni], 0, 0, 0);
                accx[mi][ni] = __builtin_amdgcn_mfma_f32_16x16x32_f16(ah[mi], bl[ni], accx[mi][ni], 0, 0, 0);
                accx[mi][ni] = __builtin_amdgcn_mfma_f32_16x16x32_f16(al[mi], bh[ni], accx[mi][ni], 0, 0, 0);
            }
    }

    // write partial C to workspace: ws[slice][row][col]
    float* wsl = ws + (size_t)slice * ((size_t)M_TOTAL * NCOL);
    #pragma unroll
    for (int mi = 0; mi < 2; ++mi)
        #pragma unroll
        for (int ni = 0; ni < 4; ++ni) {
            floatx4 v = acch[mi][ni] + accx[mi][ni] * (1.0f / 2048.0f);
            const int col   = nt0 + ni * 16 + lr;
            const int rbase = rowBase + mt0 + mi * 16 + (lane >> 4) * 4;
            #pragma unroll
            for (int reg = 0; reg < 4; ++reg)
                wsl[(size_t)(rbase + reg) * NCOL + col] = v[reg];
        }
}

__global__ __launch_bounds__(NT) void epilogue_kernel(
    const float* __restrict__ ws,
    const float* __restrict__ router_b,
    const float* __restrict__ noise_b,
    const float* __restrict__ noise_u,
    float* __restrict__ out)
{
    __shared__ struct {
        float Cs[64][132];
        float p1v[64]; float p2v[64];
        int   i1v[64]; int   i2v[64];
    } sm;

    const int t = threadIdx.x;
    const int rowBase = blockIdx.x * 64;
    const float* w0 = ws;
    const float* w1 = ws + (size_t)M_TOTAL * NCOL;

    // phase 1: combine split-K partials into LDS
    #pragma unroll
    for (int i = 0; i < 8; ++i) {
        const int f  = t + i * 256;       // 0..2047
        const int rr = f >> 5;
        const int c4 = (f & 31) * 4;
        const size_t g = (size_t)(rowBase + rr) * NCOL + c4;
        const float4 u0 = *(const float4*)&w0[g];
        const float4 u1 = *(const float4*)&w1[g];
        float4 s;
        s.x = u0.x + u1.x; s.y = u0.y + u1.y; s.z = u0.z + u1.z; s.w = u0.w + u1.w;
        *(float4*)&sm.Cs[rr][c4] = s;
    }
    __syncthreads();

    // phase 2: per-row bias + softplus-noise + top-2 + 2-term softmax
    if (t < 64) {
        const int r = t;
        const int grow = rowBase + r;
        const float* urow = noise_u + (size_t)grow * E_DIM;
        float v1 = -3.0e38f, v2 = -3.0e38f;
        int i1 = 0, i2 = 0;
        for (int e = 0; e < E_DIM; ++e) {
            const float lg = sm.Cs[r][e] + router_b[e];
            const float nz = sm.Cs[r][64 + e] + noise_b[e];
            const float sp = fmaxf(nz, 0.0f) + log1pf(expf(-fabsf(nz)));
            const float nv = lg + sp * urow[e];
            if (nv > v1) { v2 = v1; i2 = i1; v1 = nv; i1 = e; }
            else if (nv > v2) { v2 = nv; i2 = e; }
        }
        const float e2 = expf(v2 - v1);
        const float denom = 1.0f + e2;
        sm.p1v[r] = 1.0f / denom;
        sm.p2v[r] = e2 / denom;
        sm.i1v[r] = i1;
        sm.i2v[r] = i2;
        float2 idx2;
        idx2.x = (float)i1;
        idx2.y = (float)i2;
        *(float2*)&out[(size_t)M_TOTAL * E_DIM + (size_t)grow * 2] = idx2;
    }
    __syncthreads();

    // phase 3: cooperative sparse-softmax write (64 rows x 64 experts, 16/thread)
    {
        const int r  = t >> 2;
        const int eb = (t & 3) * 16;
        const int grow = rowBase + r;
        const int i1 = sm.i1v[r];
        const int i2 = sm.i2v[r];
        const float p1 = sm.p1v[r];
        const float p2 = sm.p2v[r];
        float* orow = out + (size_t)grow * E_DIM;
        #pragma unroll
        for (int g = 0; g < 4; ++g) {
            const int e0 = eb + g * 4;
            float4 v;
            v.x = (e0 + 0 == i1) ? p1 : (e0 + 0 == i2) ? p2 : 0.0f;
            v.y = (e0 + 1 == i1) ? p1 : (e0 + 1 == i2) ? p2 : 0.0f;
            v.z = (e0 + 2 == i1) ? p1 : (e0 + 2 == i2) ? p2 : 0.0f;
            v.w = (e0 + 3 == i1) ? p1 : (e0 + 3 == i2) ? p2 : 0.0f;
            *(float4*)&orow[e0] = v;
        }
    }
}

extern "C" void kernel_launch(void* const* d_in, const int* in_sizes, int n_in,
                              void* d_out, int out_size, void* d_ws, size_t ws_size,
                              hipStream_t stream) {
    const float* x  = (const float*)d_in[0];
    const float* rw = (const float*)d_in[1];
    const float* rb = (const float*)d_in[2];
    const float* nw = (const float*)d_in[3];
    const float* nb = (const float*)d_in[4];
    const float* nu = (const float*)d_in[5];
    float* out = (float*)d_out;
    float* ws  = (float*)d_ws;
    (void)in_sizes; (void)n_in; (void)out_size; (void)ws_size;

    hipLaunchKernelGGL(gemm_split_kernel, dim3((M_TOTAL / BMg) * KSLICE), dim3(NT), 0, stream,
                       x, rw, nw, ws);
    hipLaunchKernelGGL(epilogue_kernel, dim3(M_TOTAL / 64), dim3(NT), 0, stream,
                       ws, rb, nb, nu, out);
}

// Round 5
// 237.773 us; speedup vs baseline: 3.4195x; 1.0262x over previous
//
#include <hip/hip_runtime.h>
#include <math.h>

typedef __fp16   fp16x2  __attribute__((ext_vector_type(2)));
typedef _Float16 half8   __attribute__((ext_vector_type(8)));
typedef float    floatx4 __attribute__((ext_vector_type(4)));

#define M_TOTAL 16384
#define K_DIM   2048
#define NCOL    128
#define BM      32
#define BK      32
#define NT      256
#define NCHUNK  (K_DIM / BK)   // 64

// halves offsets within one LDS buffer
// layout: [Ahi 1024][Alo 1024][Bhi 4096][Blo 4096] halves = 20480 B
#define A_HI  0
#define A_LO  1024
#define B_HI  2048
#define B_LO  6144
#define BUF_H 10240

__device__ __forceinline__ void gl_lds16(const _Float16* g, _Float16* l) {
    __builtin_amdgcn_global_load_lds((const __attribute__((address_space(1))) void*)g,
                                     (__attribute__((address_space(3))) void*)l, 16, 0, 0);
}

__device__ __forceinline__ void cvt_store(const float4 v, _Float16* hiP, _Float16* loP) {
    fp16x2 h01 = __builtin_amdgcn_cvt_pkrtz(v.x, v.y);
    fp16x2 h23 = __builtin_amdgcn_cvt_pkrtz(v.z, v.w);
    float r0 = (v.x - (float)h01.x) * 2048.0f;
    float r1 = (v.y - (float)h01.y) * 2048.0f;
    float r2 = (v.z - (float)h23.x) * 2048.0f;
    float r3 = (v.w - (float)h23.y) * 2048.0f;
    fp16x2 l01 = __builtin_amdgcn_cvt_pkrtz(r0, r1);
    fp16x2 l23 = __builtin_amdgcn_cvt_pkrtz(r2, r3);
    union { fp16x2 h[2]; uint2 u; } ph, pl;
    ph.h[0] = h01; ph.h[1] = h23;
    pl.h[0] = l01; pl.h[1] = l23;
    *(uint2*)hiP = ph.u;
    *(uint2*)loP = pl.u;
}

// Pre-convert W (router||noise, fp32 [128][2048]) into ws as hi/lo f16,
// granule-major per 32-k chunk: chunk c = 8192 halves:
//   hi: [(g*128 + col)*8 + j]  (g=0..3 k-granule, col=0..127, j=0..7)
//   lo: same at +4096 halves
__global__ __launch_bounds__(256) void conv_w_kernel(
    const float* __restrict__ rw, const float* __restrict__ nw,
    _Float16* __restrict__ wsB)
{
    const int u   = blockIdx.x * 256 + threadIdx.x;  // 0..32767
    const int col = u & 127;
    const int g   = (u >> 7) & 3;
    const int c   = u >> 9;
    const float* srcRow = (col < 64) ? (rw + (size_t)col * K_DIM)
                                     : (nw + (size_t)(col - 64) * K_DIM);
    const float* src = srcRow + c * BK + g * 8;
    const float4 v0 = *(const float4*)src;
    const float4 v1 = *(const float4*)(src + 4);
    union { fp16x2 h[4]; uint4 q; } ph, pl;
    ph.h[0] = __builtin_amdgcn_cvt_pkrtz(v0.x, v0.y);
    ph.h[1] = __builtin_amdgcn_cvt_pkrtz(v0.z, v0.w);
    ph.h[2] = __builtin_amdgcn_cvt_pkrtz(v1.x, v1.y);
    ph.h[3] = __builtin_amdgcn_cvt_pkrtz(v1.z, v1.w);
    pl.h[0] = __builtin_amdgcn_cvt_pkrtz((v0.x - (float)ph.h[0].x) * 2048.0f,
                                         (v0.y - (float)ph.h[0].y) * 2048.0f);
    pl.h[1] = __builtin_amdgcn_cvt_pkrtz((v0.z - (float)ph.h[1].x) * 2048.0f,
                                         (v0.w - (float)ph.h[1].y) * 2048.0f);
    pl.h[2] = __builtin_amdgcn_cvt_pkrtz((v1.x - (float)ph.h[2].x) * 2048.0f,
                                         (v1.y - (float)ph.h[2].y) * 2048.0f);
    pl.h[3] = __builtin_amdgcn_cvt_pkrtz((v1.z - (float)ph.h[3].x) * 2048.0f,
                                         (v1.w - (float)ph.h[3].y) * 2048.0f);
    const size_t base = (size_t)c * 8192 + ((size_t)g * 128 + col) * 8;
    *(uint4*)&wsB[base]        = ph.q;
    *(uint4*)&wsB[base + 4096] = pl.q;
}

__global__ __launch_bounds__(NT, 2) void gemm_router_kernel(
    const float* __restrict__ x,
    const _Float16* __restrict__ wsB,
    const float* __restrict__ router_b,
    const float* __restrict__ noise_b,
    const float* __restrict__ noise_u,
    float* __restrict__ out)
{
    __shared__ __align__(16) union {
        _Float16 S[2 * BUF_H];
        struct { float Cs[32][132]; float p1[32]; float p2[32]; int i1[32]; int i2[32]; } e;
    } sm;

    const int t    = threadIdx.x;
    const int lane = t & 63;
    const int w    = t >> 6;
    const int rowBase = blockIdx.x * BM;

    // A staging map: thread -> (row r, k-quad q)
    const int r = t >> 3, q = t & 7;
    const float* pa = x + (size_t)(rowBase + r) * K_DIM + q * 4;
    const int aw = ((q >> 1) * 32 + r) * 8 + (q & 1) * 4;  // halves, granule-major [g][row]

    // fragment map: wave w -> rows mt0..+16, cols nt0..+64
    const int lr  = lane & 15;
    const int lg4 = lane >> 4;
    const int mt0 = (w & 1) * 16;
    const int nt0 = (w >> 1) * 64;
    const int aOff = (lg4 * 32 + mt0 + lr) * 8;

    floatx4 acch[4], accx[4];
    #pragma unroll
    for (int ni = 0; ni < 4; ++ni) { acch[ni] = (floatx4)0.0f; accx[ni] = (floatx4)0.0f; }

    // prologue: chunk 0
    float4 aReg = *(const float4*)pa;
    {
        #pragma unroll
        for (int i = 0; i < 4; ++i) {
            const int n = w * 4 + i;
            gl_lds16(wsB + n * 512 + lane * 8, &sm.S[B_HI + n * 512]);
        }
    }
    cvt_store(aReg, &sm.S[A_HI + aw], &sm.S[A_LO + aw]);

    for (int c = 0; c < NCHUNK; ++c) {
        __syncthreads();  // B(c) arrived, A(c) staged, buf[(c+1)&1] reads done
        _Float16* buf  = sm.S + (c & 1) * BUF_H;
        _Float16* bufn = sm.S + ((c + 1) & 1) * BUF_H;

        if (c + 1 < NCHUNK) {
            const _Float16* wc = wsB + (size_t)(c + 1) * 8192;
            #pragma unroll
            for (int i = 0; i < 4; ++i) {
                const int n = w * 4 + i;
                gl_lds16(wc + n * 512 + lane * 8, bufn + B_HI + n * 512);
            }
            aReg = *(const float4*)(pa + (c + 1) * BK);
        }

        const half8 ah = *(const half8*)&buf[A_HI + aOff];
        const half8 al = *(const half8*)&buf[A_LO + aOff];
        half8 bh[4], bl[4];
        #pragma unroll
        for (int ni = 0; ni < 4; ++ni) {
            const int bo = (lg4 * 128 + nt0 + ni * 16 + lr) * 8;
            bh[ni] = *(const half8*)&buf[B_HI + bo];
            bl[ni] = *(const half8*)&buf[B_LO + bo];
        }
        #pragma unroll
        for (int ni = 0; ni < 4; ++ni) {
            acch[ni] = __builtin_amdgcn_mfma_f32_16x16x32_f16(ah, bh[ni], acch[ni], 0, 0, 0);
            accx[ni] = __builtin_amdgcn_mfma_f32_16x16x32_f16(ah, bl[ni], accx[ni], 0, 0, 0);
            accx[ni] = __builtin_amdgcn_mfma_f32_16x16x32_f16(al, bh[ni], accx[ni], 0, 0, 0);
        }
        if (c + 1 < NCHUNK)
            cvt_store(aReg, &bufn[A_HI + aw], &bufn[A_LO + aw]);
    }

    // ---- fused epilogue ----
    // chunk 63 used buf1 (halves 10240..); Cs occupies halves 0..8448 -> no race
    #pragma unroll
    for (int ni = 0; ni < 4; ++ni) {
        const floatx4 v = acch[ni] + accx[ni] * (1.0f / 2048.0f);
        const int col = nt0 + ni * 16 + lr;
        #pragma unroll
        for (int reg = 0; reg < 4; ++reg)
            sm.e.Cs[mt0 + lg4 * 4 + reg][col] = v[reg];
    }
    __syncthreads();

    // per-row top-2: 8 threads/row, 8 experts each, shuffle merge
    {
        const int sr = t >> 3;          // row 0..31
        const int eg = (t & 7) * 8;     // expert base
        const int grow = rowBase + sr;
        const float* urow = noise_u + (size_t)grow * 64 + eg;
        const float4 u0 = *(const float4*)urow;
        const float4 u1 = *(const float4*)(urow + 4);
        const float uu[8] = {u0.x, u0.y, u0.z, u0.w, u1.x, u1.y, u1.z, u1.w};
        float v1 = -3.0e38f, v2 = -3.0e38f;
        int i1 = 0, i2 = 0;
        #pragma unroll
        for (int j = 0; j < 8; ++j) {
            const int e = eg + j;
            const float lg = sm.e.Cs[sr][e] + router_b[e];
            const float nz = sm.e.Cs[sr][64 + e] + noise_b[e];
            const float sp = fmaxf(nz, 0.0f) + log1pf(expf(-fabsf(nz)));
            const float nv = lg + sp * uu[j];
            if (nv > v1)      { v2 = v1; i2 = i1; v1 = nv; i1 = e; }
            else if (nv > v2) { v2 = nv; i2 = e; }
        }
        #pragma unroll
        for (int m = 1; m < 8; m <<= 1) {
            const float ov1 = __shfl_xor(v1, m, 64);
            const int   oi1 = __shfl_xor(i1, m, 64);
            const float ov2 = __shfl_xor(v2, m, 64);
            const int   oi2 = __shfl_xor(i2, m, 64);
            const bool takeO = (ov1 > v1) || (ov1 == v1 && oi1 < i1);
            const float t1v = takeO ? ov1 : v1;  const int t1i = takeO ? oi1 : i1;
            const float c2v = takeO ? v1 : ov1;  const int c2i = takeO ? i1 : oi1;
            const float c3v = takeO ? ov2 : v2;  const int c3i = takeO ? oi2 : i2;
            const bool k2 = (c3v > c2v) || (c3v == c2v && c3i < c2i);
            v1 = t1v; i1 = t1i;
            v2 = k2 ? c3v : c2v; i2 = k2 ? c3i : c2i;
        }
        if ((t & 7) == 0) {
            const float e2 = expf(v2 - v1);
            const float dn = 1.0f + e2;   // other 62 slots: exp(-1e30 - m) == 0
            sm.e.p1[sr] = 1.0f / dn;
            sm.e.p2[sr] = e2 / dn;
            sm.e.i1[sr] = i1;
            sm.e.i2[sr] = i2;
            float2 idx2;
            idx2.x = (float)i1;
            idx2.y = (float)i2;
            *(float2*)&out[(size_t)M_TOTAL * 64 + (size_t)grow * 2] = idx2;
        }
    }
    __syncthreads();

    // cooperative sparse-softmax write: 32 rows x 64 experts, 8 floats/thread
    {
        const int rr = t >> 3;
        const int e0 = (t & 7) * 8;
        const int g2 = rowBase + rr;
        const int j1 = sm.e.i1[rr], j2 = sm.e.i2[rr];
        const float q1 = sm.e.p1[rr], q2 = sm.e.p2[rr];
        float* orow = out + (size_t)g2 * 64;
        #pragma unroll
        for (int g = 0; g < 2; ++g) {
            const int b0 = e0 + g * 4;
            float4 v;
            v.x = (b0 + 0 == j1) ? q1 : (b0 + 0 == j2) ? q2 : 0.0f;
            v.y = (b0 + 1 == j1) ? q1 : (b0 + 1 == j2) ? q2 : 0.0f;
            v.z = (b0 + 2 == j1) ? q1 : (b0 + 2 == j2) ? q2 : 0.0f;
            v.w = (b0 + 3 == j1) ? q1 : (b0 + 3 == j2) ? q2 : 0.0f;
            *(float4*)&orow[b0] = v;
        }
    }
}

extern "C" void kernel_launch(void* const* d_in, const int* in_sizes, int n_in,
                              void* d_out, int out_size, void* d_ws, size_t ws_size,
                              hipStream_t stream) {
    const float* x  = (const float*)d_in[0];
    const float* rw = (const float*)d_in[1];
    const float* rb = (const float*)d_in[2];
    const float* nw = (const float*)d_in[3];
    const float* nb = (const float*)d_in[4];
    const float* nu = (const float*)d_in[5];
    float* out = (float*)d_out;
    _Float16* wsB = (_Float16*)d_ws;
    (void)in_sizes; (void)n_in; (void)out_size; (void)ws_size;

    hipLaunchKernelGGL(conv_w_kernel, dim3(128), dim3(256), 0, stream, rw, nw, wsB);
    hipLaunchKernelGGL(gemm_router_kernel, dim3(M_TOTAL / BM), dim3(NT), 0, stream,
                       x, wsB, rb, nb, nu, out);
}